// Round 7
// baseline (4771.752 us; speedup 1.0000x reference)
//
#include <hip/hip_runtime.h>
#include <hip/hip_bf16.h>

// Problem constants
#define BB 32
#define SS 512
#define DD 256
#define HH 256
#define GG 1024          // 4*H
#define MM (SS*BB)       // 16384 rows, m = s*32 + b
#define NSENT 16
#define TT 12
#define TAG_START 10
#define TAG_STOP 11

typedef unsigned long long u64;
typedef unsigned int u32;

__device__ __forceinline__ float sigm(float x) {
  x = fminf(fmaxf(x, -15.f), 15.f);
  return 1.f / (1.f + __expf(-x));
}
__device__ __forceinline__ float tanh_fast(float x) {
  x = fminf(fmaxf(x, -15.f), 15.f);
  float e = __expf(2.f * x);
  return (e - 1.f) / (e + 1.f);
}

// ---------------- embed gather: X1[m][d] = embed[inputs[b][s]][d], m = s*32+b
__global__ void embed_kernel(const int* __restrict__ toks, const float* __restrict__ emb,
                             float* __restrict__ X1) {
  int m = blockIdx.x;
  int s = m >> 5, b = m & 31;
  int tok = toks[b * SS + s];
  ((float4*)(X1 + (size_t)m * DD))[threadIdx.x] =
      ((const float4*)(emb + (size_t)tok * DD))[threadIdx.x];
}

// ---------------- fp32 NT GEMM (R9-verified core + z-batching):
// C[M,N] = A[M,K](lda) @ W[N,K](ldw)^T + bias.  128x128 tile, 8x8/thread.
// blockIdx.z selects direction: W += z*wz, C += z*cz, bias += z*GG.
__launch_bounds__(256)
__global__ void gemm_nt(const float* __restrict__ A, const float* __restrict__ W_,
                        const float* __restrict__ bias_, float* __restrict__ C_,
                        int K, int lda, int ldw, int ldC, size_t wz, size_t cz) {
  __shared__ float As[16 * 132];
  __shared__ float Ws[16 * 132];
  const float* W = W_ + (size_t)blockIdx.z * wz;
  const float* bias = bias_ ? bias_ + (size_t)blockIdx.z * GG : nullptr;
  float* C = C_ + (size_t)blockIdx.z * cz;
  const int tid = threadIdx.x;
  const int n0 = blockIdx.x * 128, m0 = blockIdx.y * 128;
  const int row = tid & 127, half = tid >> 7;    // staging: 128 rows x 2 k-halves
  const int tx = tid & 15, ty = tid >> 4;        // compute: 16x16 thread grid
  float acc[8][8] = {};
  const float* Arow = A + (size_t)(m0 + row) * lda;
  const float* Wrow = W + (size_t)(n0 + row) * ldw;
  for (int kk = 0; kk < K; kk += 16) {
    const int kb = half * 8;
    float4 a0 = *(const float4*)(Arow + kk + kb);
    float4 a1 = *(const float4*)(Arow + kk + kb + 4);
    float4 w0 = *(const float4*)(Wrow + kk + kb);
    float4 w1 = *(const float4*)(Wrow + kk + kb + 4);
    As[(kb + 0) * 132 + row] = a0.x; As[(kb + 1) * 132 + row] = a0.y;
    As[(kb + 2) * 132 + row] = a0.z; As[(kb + 3) * 132 + row] = a0.w;
    As[(kb + 4) * 132 + row] = a1.x; As[(kb + 5) * 132 + row] = a1.y;
    As[(kb + 6) * 132 + row] = a1.z; As[(kb + 7) * 132 + row] = a1.w;
    Ws[(kb + 0) * 132 + row] = w0.x; Ws[(kb + 1) * 132 + row] = w0.y;
    Ws[(kb + 2) * 132 + row] = w0.z; Ws[(kb + 3) * 132 + row] = w0.w;
    Ws[(kb + 4) * 132 + row] = w1.x; Ws[(kb + 5) * 132 + row] = w1.y;
    Ws[(kb + 6) * 132 + row] = w1.z; Ws[(kb + 7) * 132 + row] = w1.w;
    __syncthreads();
#pragma unroll
    for (int kl = 0; kl < 16; ++kl) {
      const float4 alo = *(const float4*)&As[kl * 132 + ty * 4];
      const float4 ahi = *(const float4*)&As[kl * 132 + 64 + ty * 4];
      const float4 wlo = *(const float4*)&Ws[kl * 132 + tx * 4];
      const float4 whi = *(const float4*)&Ws[kl * 132 + 64 + tx * 4];
      const float am[8] = {alo.x, alo.y, alo.z, alo.w, ahi.x, ahi.y, ahi.z, ahi.w};
      const float wm[8] = {wlo.x, wlo.y, wlo.z, wlo.w, whi.x, whi.y, whi.z, whi.w};
#pragma unroll
      for (int i = 0; i < 8; ++i)
#pragma unroll
        for (int j = 0; j < 8; ++j) acc[i][j] = fmaf(am[i], wm[j], acc[i][j]);
    }
    __syncthreads();
  }
  float4 blo = make_float4(0.f, 0.f, 0.f, 0.f), bhi = blo;
  if (bias) {
    blo = *(const float4*)(bias + n0 + tx * 4);
    bhi = *(const float4*)(bias + n0 + 64 + tx * 4);
  }
#pragma unroll
  for (int i = 0; i < 8; ++i) {
    const int m = m0 + ((i < 4) ? (ty * 4 + i) : (64 + ty * 4 + i - 4));
    float4 lo = make_float4(acc[i][0] + blo.x, acc[i][1] + blo.y,
                            acc[i][2] + blo.z, acc[i][3] + blo.w);
    float4 hi = make_float4(acc[i][4] + bhi.x, acc[i][5] + bhi.y,
                            acc[i][6] + bhi.z, acc[i][7] + bhi.w);
    *(float4*)(C + (size_t)m * ldC + n0 + tx * 4) = lo;
    *(float4*)(C + (size_t)m * ldC + n0 + 64 + tx * 4) = hi;
  }
}

// ---------------- 512x512 transpose (for attW^T), 32x32 LDS tiles
__global__ void transpose512(const float* __restrict__ in, float* __restrict__ out) {
  __shared__ float tile[32][33];
  const int bx = blockIdx.x & 15, by = blockIdx.x >> 4;
  const int tx = threadIdx.x & 31, ty = threadIdx.x >> 5;  // 32x8
  for (int i = 0; i < 32; i += 8)
    tile[ty + i][tx] = in[(size_t)(by * 32 + ty + i) * 512 + bx * 32 + tx];
  __syncthreads();
  for (int i = 0; i < 32; i += 8)
    out[(size_t)(bx * 32 + ty + i) * 512 + by * 32 + tx] = tile[tx][ty + i];
}

// ---------------- whh repack (R3-verified layout): [d][sl][i4(32)][t(256)][4],
// t = half*128 + r; value = whh[d][gcol(r,sl)][half*128 + i4*4 + c].
__global__ void prep_whh(const float* __restrict__ whh1, const float* __restrict__ whh2,
                         float* __restrict__ o1, float* __restrict__ o2) {
  int idx0 = blockIdx.x * 256 + threadIdx.x;       // 2 * 524288
  int layer = idx0 >> 19;
  int idx = idx0 & 524287;
  const float* whh = layer ? whh2 : whh1;
  float* out = layer ? o2 : o1;
  int c    = idx & 3;
  int t    = (idx >> 2) & 255;
  int i4   = (idx >> 10) & 31;
  int sl   = (idx >> 15) & 7;
  int d    = idx >> 18;
  int r    = t & 127;
  int half = t >> 7;
  int g = (r >> 5) * 256 + sl * 32 + (r & 31);
  int k = half * 128 + i4 * 4 + c;
  out[idx] = whh[(size_t)(d * GG + g) * HH + k];
}

// ---------------- LSTM recurrence — R6-verified structure (256 thr, per-thread
// 2-word polls, k-split w[128] in VGPRs, p_lds combine, tid<64 epilogue,
// att folded in rec2, post-(c) hist). R7 change: HYBRID POLL.
//   Evidence (R6 PMC): VALUBusy & FETCH_SIZE imply ~30-45 poll rounds/step at
//   ~150cy period — the step is dominated by store->visibility latency of the
//   agent(sc1) path. Group wgs (bids ≡ chain mod 8) share an XCD under
//   round-robin dispatch, where the producer's PLAIN store is visible in the
//   local L2 in ~150cy. So: producer = plain store (local L2, fast) + agent
//   store (global, correct); consumer = sc0 polls (L1-bypass, L2-read) with
//   every-4th-iteration agent escalation. Stale sc0 reads fail the tag check;
//   the agent load is guaranteed fresh -> correct for ANY XCD placement.
//   (Each 64B hx line is written by exactly ONE wg -> no cross-wg dirty-line
//   sharing on plain stores.)
__launch_bounds__(256, 1)
__global__ void rec_kernel(const float* __restrict__ Xp, const float* __restrict__ whh_p,
                           float* __restrict__ hist, u64* __restrict__ hx,
                           const float* __restrict__ aw, const float* __restrict__ sentW,
                           int useAtt) {
  __shared__ float h_lds[512];       // [c*256 + k]
  __shared__ float p_lds[512];       // [(half*128 + r)*2 + c]
  const int tid = threadIdx.x;
  const int bid = blockIdx.x;
  const int sl = bid >> 5;
  const int db = bid & 31;
  const int d = db & 1;
  const int bg = db >> 1;
  const int r = tid & 127;           // gate row 0..127 (gate*32+j)
  const int half = tid >> 7;         // k-half: k in [half*128, half*128+128)
  // -------- register-resident whh half-row (w[128]/thread; ~166 VGPR, no spill)
  const float* wp = whh_p + (size_t)(d * 8 + sl) * 32768;
  float w[128];
#pragma unroll
  for (int i4 = 0; i4 < 32; ++i4) {
    const float4 v = *(const float4*)&wp[(size_t)(i4 * 256 + tid) * 4];
    w[i4 * 4 + 0] = v.x; w[i4 * 4 + 1] = v.y;
    w[i4 * 4 + 2] = v.z; w[i4 * 4 + 3] = v.w;
  }
  const float* XpD = Xp + (size_t)d * MM * GG;
  const int gcol = (r >> 5) * 256 + sl * 32 + (r & 31);
  const int jj = tid & 31, cc = tid >> 5;        // producer epilogue mapping (tid<64)
  const int histMine = ((r >> 4) == sl);         // my 2 polled words in my hist slice
  float creg = 0.f;                              // LSTM cell state (valid tid<64)
  // register-cached sentW columns; rank-16 att split by k-half (8 terms each)
  float swA[8], swB[8];
  if (useAtt) {
    const float* swp = sentW + ((size_t)d * 512 + (size_t)(bg * 2) * 16) * 1024 + gcol;
#pragma unroll
    for (int n = 0; n < 8; ++n) {
      swA[n] = swp[(size_t)(half * 8 + n) * 1024];
      swB[n] = swp[(size_t)(16 + half * 8 + n) * 1024];
    }
  }
  // group base: hx[slot][d][bg][512]
  u64* grp[2] = { hx + ((size_t)(0 * 2 + d) * 16 + bg) * 512,
                  hx + ((size_t)(1 * 2 + d) * 16 + bg) * 512 };
#pragma unroll 1
  for (int t = 0; t < SS; ++t) {
    const int s = d ? (SS - 1 - t) : t;
    // xp loads + aw loads issued before the spin (latency hidden under spin)
    const int m0 = s * BB + bg * 2;
    float x0 = 0.f, x1 = 0.f;
    if (half == 0) {
      x0 = XpD[(size_t)m0 * GG + gcol];
      x1 = XpD[(size_t)(m0 + 1) * GG + gcol];
    }
    if (useAtt) {
      const float* a0 = aw + (size_t)m0 * 16;     // rows m0, m0+1 contiguous
#pragma unroll
      for (int n = 0; n < 8; ++n) {
        x0 = fmaf(a0[half * 8 + n], swA[n], x0);
        x1 = fmaf(a0[16 + half * 8 + n], swB[n], x1);
      }
    }
    // ---- hybrid spin on my 2 tagged words: sc0 fast path + agent escalation ----
    u64 w0, w1;
    {
      u64* base = grp[t & 1] + tid * 2;
      int spin = 0;
      for (;;) {
        if ((spin & 3) == 1) {   // escalation: guaranteed-fresh agent loads
          w0 = __hip_atomic_load(base + 0, __ATOMIC_RELAXED, __HIP_MEMORY_SCOPE_AGENT);
          w1 = __hip_atomic_load(base + 1, __ATOMIC_RELAXED, __HIP_MEMORY_SCOPE_AGENT);
        } else {                 // fast path: L1-bypass L2-read (same-XCD fresh)
          asm volatile("global_load_dwordx2 %0, %2, off sc0\n\t"
                       "global_load_dwordx2 %1, %2, off offset:8 sc0\n\t"
                       "s_waitcnt vmcnt(0)"
                       : "=v"(w0), "=v"(w1) : "v"(base) : "memory");
        }
        if (((u32)(w0 >> 32) == (u32)t) & ((u32)(w1 >> 32) == (u32)t)) break;
        ++spin;
        __builtin_amdgcn_s_sleep(1);
      }
    }
    *(float2*)&h_lds[tid * 2] = make_float2(__uint_as_float((u32)w0),
                                            __uint_as_float((u32)w1));
    __syncthreads();   // (b) h_lds complete
    {
      // matvec: 4 independent accumulator chains; w from regs, h broadcast LDS
      const int kb = half * 128;
      float p0a = 0.f, p0b = 0.f, p1a = 0.f, p1b = 0.f;
#pragma unroll
      for (int k8 = 0; k8 < 16; ++k8) {
        const float4 h0a = *(const float4*)&h_lds[kb + k8 * 8];
        const float4 h0b = *(const float4*)&h_lds[kb + k8 * 8 + 4];
        const float4 h1a = *(const float4*)&h_lds[256 + kb + k8 * 8];
        const float4 h1b = *(const float4*)&h_lds[256 + kb + k8 * 8 + 4];
        p0a = fmaf(w[k8*8+0], h0a.x, p0a); p0a = fmaf(w[k8*8+1], h0a.y, p0a);
        p0a = fmaf(w[k8*8+2], h0a.z, p0a); p0a = fmaf(w[k8*8+3], h0a.w, p0a);
        p0b = fmaf(w[k8*8+4], h0b.x, p0b); p0b = fmaf(w[k8*8+5], h0b.y, p0b);
        p0b = fmaf(w[k8*8+6], h0b.z, p0b); p0b = fmaf(w[k8*8+7], h0b.w, p0b);
        p1a = fmaf(w[k8*8+0], h1a.x, p1a); p1a = fmaf(w[k8*8+1], h1a.y, p1a);
        p1a = fmaf(w[k8*8+2], h1a.z, p1a); p1a = fmaf(w[k8*8+3], h1a.w, p1a);
        p1b = fmaf(w[k8*8+4], h1b.x, p1b); p1b = fmaf(w[k8*8+5], h1b.y, p1b);
        p1b = fmaf(w[k8*8+6], h1b.z, p1b); p1b = fmaf(w[k8*8+7], h1b.w, p1b);
      }
      *(float2*)&p_lds[tid * 2] = make_float2(p0a + p0b + x0, p1a + p1b + x1);
    }
    __syncthreads();   // (c) p_lds ready; fences h_lds reads vs next-step writes
    if (tid < 64) {    // producer epilogue: combine k-halves, dual store
      const float iv = p_lds[(jj) * 2 + cc]       + p_lds[(128 + jj) * 2 + cc];
      const float fv = p_lds[(32 + jj) * 2 + cc]  + p_lds[(128 + 32 + jj) * 2 + cc];
      const float gv = p_lds[(64 + jj) * 2 + cc]  + p_lds[(128 + 64 + jj) * 2 + cc];
      const float ov = p_lds[(96 + jj) * 2 + cc]  + p_lds[(128 + 96 + jj) * 2 + cc];
      const float cs = sigm(fv) * creg + sigm(iv) * tanh_fast(gv);
      creg = cs;
      const float hn = sigm(ov) * tanh_fast(cs);
      u64 wv = ((u64)(u32)(t + 1) << 32) | (u64)__float_as_uint(hn);
      u64* dst = grp[(t + 1) & 1] + cc * 256 + sl * 32 + jj;
      *(volatile u64*)dst = wv;   // fast local-L2 visibility (same-XCD consumers)
      __hip_atomic_store(dst, wv, __ATOMIC_RELAXED, __HIP_MEMORY_SCOPE_AGENT);
    }
    // distributed hist write for step t-1 (off critical path, R6-verified spot)
    if (histMine && t > 0) {
      const int sp = d ? (SS - t) : (t - 1);
      *(float2*)&hist[(size_t)(sp * BB + bg * 2 + half) * 512 + d * 256 + r * 2] =
          make_float2(__uint_as_float((u32)w0), __uint_as_float((u32)w1));
    }
  }
  // distributed final flush (tag SS): pure agent polls (rare path, verified)
  if (histMine) {
    u64* base = grp[SS & 1] + tid * 2;
    u64 w0, w1;
    do {
      w0 = __hip_atomic_load(base + 0, __ATOMIC_RELAXED, __HIP_MEMORY_SCOPE_AGENT);
      w1 = __hip_atomic_load(base + 1, __ATOMIC_RELAXED, __HIP_MEMORY_SCOPE_AGENT);
      if (((u32)(w0 >> 32) == (u32)SS) & ((u32)(w1 >> 32) == (u32)SS)) break;
      __builtin_amdgcn_s_sleep(1);
    } while (true);
    const int sp = d ? 0 : (SS - 1);
    *(float2*)&hist[(size_t)(sp * BB + bg * 2 + half) * 512 + d * 256 + r * 2] =
        make_float2(__uint_as_float((u32)w0), __uint_as_float((u32)w1));
  }
}

// ---------------- aw: scores over NS=16 sentence embs + softmax -> aw[m][16]
// (R7: inputs are word rows + SW[b][n][e] = attW^T @ sent — algebraically
// identical to wx@sent, so the kernel body is unchanged)
__global__ void aw_kernel(const float* __restrict__ wx, const float* __restrict__ sent,
                          float* __restrict__ awout) {
  __shared__ float sl[NSENT * 512];   // 32 KB
  __shared__ float wxr[512];
  __shared__ float parts[256];
  __shared__ float avals[NSENT];
  __shared__ float red0;
  const int tid = threadIdx.x;
  const int b = blockIdx.y;
  const int s0 = blockIdx.x * 32;
  for (int i = tid; i < NSENT * 512; i += 256) sl[i] = sent[(size_t)b * NSENT * 512 + i];
  __syncthreads();
  for (int si = 0; si < 32; ++si) {
    const int m = (s0 + si) * BB + b;
    for (int i = tid; i < 512; i += 256) wxr[i] = wx[(size_t)m * 512 + i];
    __syncthreads();
    const int n = tid >> 4, kp = tid & 15;
    float p = 0.f;
#pragma unroll 8
    for (int f = kp * 32; f < kp * 32 + 32; ++f) p = fmaf(wxr[f], sl[n * 512 + f], p);
    parts[tid] = p;
    __syncthreads();
    if (tid < NSENT) {
      float sc = 0.f;
      for (int qq = 0; qq < 16; ++qq) sc += parts[tid * 16 + qq];
      avals[tid] = sc;
    }
    __syncthreads();
    if (tid == 0) {
      float mx = avals[0];
      for (int qq = 1; qq < NSENT; ++qq) mx = fmaxf(mx, avals[qq]);
      float sm = 0.f;
      for (int qq = 0; qq < NSENT; ++qq) { float e = expf(avals[qq] - mx); avals[qq] = e; sm += e; }
      red0 = 1.f / sm;
    }
    __syncthreads();
    if (tid < NSENT) awout[(size_t)m * 16 + tid] = avals[tid] * red0;
    __syncthreads();
  }
}

// ---------------- feats[m][t] = l2m[m][:] . h2t_w[t][:] + h2t_b[t]; wave per row
__global__ void feats_kernel(const float* __restrict__ l2m, const float* __restrict__ w,
                             const float* __restrict__ bias, float* __restrict__ feats) {
  const int wave = threadIdx.x >> 6, lane = threadIdx.x & 63;
  const int m = blockIdx.x * 4 + wave;
  const float* row = l2m + (size_t)m * 512;
  float rv[8];
#pragma unroll
  for (int i = 0; i < 8; ++i) rv[i] = row[lane + i * 64];
  for (int t = 0; t < TT; ++t) {
    const float* wr = w + t * 512;
    float p = 0.f;
#pragma unroll
    for (int i = 0; i < 8; ++i) p = fmaf(rv[i], wr[lane + i * 64], p);
#pragma unroll
    for (int off = 32; off; off >>= 1) p += __shfl_down(p, off);
    if (lane == 0) feats[(size_t)m * TT + t] = p + bias[t];
  }
}

// ---------------- viterbi per batch; 1 wave, whole DP in LDS
__global__ void viterbi_kernel(const float* __restrict__ feats, const float* __restrict__ trans,
                               int* __restrict__ out) {
  __shared__ float flds[SS * TT];
  __shared__ unsigned char bp[SS * TT];
  __shared__ float tr[TT * TT];
  __shared__ float fv[TT];
  __shared__ float tv[TT];
  __shared__ int pathS[SS];
  const int b = blockIdx.x, tid = threadIdx.x;
  for (int i = tid; i < SS * TT; i += 64) {
    int s = i / TT, t = i - s * TT;
    flds[i] = feats[(size_t)(s * BB + b) * TT + t];
  }
  for (int i = tid; i < TT * TT; i += 64) tr[i] = trans[i];
  if (tid < TT) fv[tid] = (tid == TAG_START) ? 0.f : -10000.f;
  __syncthreads();
  for (int s = 0; s < SS; ++s) {
    float nf = 0.f;
    if (tid < TT) {
      float mx = -1e30f;
      int bj = 0;
#pragma unroll
      for (int jj = 0; jj < TT; ++jj) {
        float v = fv[jj] + tr[tid * TT + jj];
        if (v > mx) { mx = v; bj = jj; }
      }
      nf = mx + flds[s * TT + tid];
      bp[s * TT + tid] = (unsigned char)bj;
    }
    __syncthreads();
    if (tid < TT) fv[tid] = nf;
    __syncthreads();
  }
  if (tid < TT) tv[tid] = fv[tid] + tr[TAG_STOP * TT + tid];
  __syncthreads();
  if (tid == 0) {
    int best = 0;
    float mx = tv[0];
    for (int jj = 1; jj < TT; ++jj)
      if (tv[jj] > mx) { mx = tv[jj]; best = jj; }
    pathS[SS - 1] = best;
    for (int s = SS - 1; s > 0; --s) { best = bp[s * TT + best]; pathS[s - 1] = best; }
  }
  __syncthreads();
  for (int s = tid; s < SS; s += 64) out[b * SS + s] = pathS[s];
}

// ---------------- workspace layout (bytes) — total ~245.6 MB < 256 MB ----------------
#define OFF_XP    ((size_t)0)               // 2*16384*1024*4 = 134217728
#define OFF_WX    ((size_t)134217728)       // region reused: attWT/SW/Weff (6 MB)
#define OFF_L2M   ((size_t)167772160)       // 16384*512*4 = 33554432 (X1 aliases here)
#define OFF_WORD  ((size_t)201326592)       // 16384*512*4 = 33554432
#define OFF_WT1   ((size_t)234881024)       // 2097152
#define OFF_WT2   ((size_t)236978176)       // 2097152
#define OFF_FEATS ((size_t)239075328)       // 786432
#define OFF_HX1   ((size_t)239861760)       // 262144
#define OFF_HX2   ((size_t)240123904)       // 262144
#define OFF_SENTW ((size_t)240386048)       // 2*512*1024*4 = 4194304
#define OFF_AW    ((size_t)244580352)       // 16384*16*4 = 1048576
#define OFF_ATTWT (OFF_WX)                  // 512*512*4 = 1048576
#define OFF_SW    (OFF_WX + (size_t)1048576)   // 32*16*512*4 = 1048576
#define OFF_WEFF  (OFF_WX + (size_t)2097152)   // 2*1024*512*4 = 4194304

extern "C" void kernel_launch(void* const* d_in, const int* in_sizes, int n_in,
                              void* d_out, int out_size, void* d_ws, size_t ws_size,
                              hipStream_t stream) {
  const int* inputs  = (const int*)d_in[0];
  const float* sent  = (const float*)d_in[1];
  const float* emb   = (const float*)d_in[2];
  const float* l1wih = (const float*)d_in[3];
  const float* l1whh = (const float*)d_in[4];
  const float* l1b   = (const float*)d_in[5];
  const float* l2wih = (const float*)d_in[6];
  const float* l2whh = (const float*)d_in[7];
  const float* l2b   = (const float*)d_in[8];
  const float* attW  = (const float*)d_in[9];
  const float* h2tw  = (const float*)d_in[10];
  const float* h2tb  = (const float*)d_in[11];
  const float* trans = (const float*)d_in[12];
  int* out = (int*)d_out;
  char* ws = (char*)d_ws;

  float* Xp    = (float*)(ws + OFF_XP);
  float* l2m   = (float*)(ws + OFF_L2M);
  float* X1    = l2m;    // X1 dead (read only by l1 gemms) before rec2 writes l2m
  float* word  = (float*)(ws + OFF_WORD);
  float* wt1   = (float*)(ws + OFF_WT1);
  float* wt2   = (float*)(ws + OFF_WT2);
  float* feats = (float*)(ws + OFF_FEATS);
  u64* hx1     = (u64*)(ws + OFF_HX1);
  u64* hx2     = (u64*)(ws + OFF_HX2);
  float* sentW = (float*)(ws + OFF_SENTW);
  float* awb   = (float*)(ws + OFF_AW);
  float* attWT = (float*)(ws + OFF_ATTWT);
  float* SWp   = (float*)(ws + OFF_SW);
  float* Weff  = (float*)(ws + OFF_WEFF);

  // zero both tagged-h buffers (contiguous 512 KB): tag 0 == "h_{-1}=0 ready"
  (void)hipMemsetAsync(ws + OFF_HX1, 0, 262144 * 2, stream);

  prep_whh<<<4096, 256, 0, stream>>>(l1whh, l2whh, wt1, wt2);
  // attWT[e][f] = attW[f][e]
  transpose512<<<256, 256, 0, stream>>>(attW, attWT);
  // sentW[d][b*16+n][g] = sent[b][n][:512] . l2wih[d][g][512:1024]
  gemm_nt<<<dim3(8, 4, 2), 256, 0, stream>>>(sent, l2wih + 512, nullptr, sentW,
                                             512, 512, GG, 1024,
                                             (size_t)GG * GG, (size_t)512 * 1024);
  // Weff[d][g][e] = sum_f l2wih[d][g][f<512] * attW[f][e]  (wx-gemm fold)
  gemm_nt<<<dim3(4, 8, 1), 256, 0, stream>>>(l2wih, attWT, nullptr, Weff,
                                             512, GG, 512, 512, 0, 0);
  gemm_nt<<<dim3(4, 8, 1), 256, 0, stream>>>(l2wih + (size_t)GG * GG, attWT, nullptr,
                                             Weff + (size_t)1024 * 512,
                                             512, GG, 512, 512, 0, 0);
  // SW[b*16+n][e] = sum_f sent[b][n][f] * attW[f][e]
  gemm_nt<<<dim3(4, 4, 1), 256, 0, stream>>>(sent, attWT, nullptr, SWp,
                                             512, 512, 512, 512, 0, 0);
  embed_kernel<<<MM, 64, 0, stream>>>(inputs, emb, X1);
  gemm_nt<<<dim3(8, 128, 2), 256, 0, stream>>>(X1, l1wih, l1b, Xp,
                                               DD, DD, DD, GG,
                                               (size_t)GG * DD, (size_t)MM * GG);
  rec_kernel<<<256, 256, 0, stream>>>(Xp, wt1, word, hx1, nullptr, nullptr, 0);
  // aw from word directly (scores = word @ SW^T per batch)
  aw_kernel<<<dim3(16, 32), 256, 0, stream>>>(word, SWp, awb);
  // Xp2 = word @ Weff^T + bias  (wx never materialized)
  gemm_nt<<<dim3(8, 128, 2), 256, 0, stream>>>(word, Weff, l2b, Xp,
                                               512, 512, 512, GG,
                                               (size_t)1024 * 512, (size_t)MM * GG);
  rec_kernel<<<256, 256, 0, stream>>>(Xp, wt2, l2m, hx2, awb, sentW, 1);
  feats_kernel<<<MM / 4, 256, 0, stream>>>(l2m, h2tw, h2tb, feats);
  viterbi_kernel<<<BB, 64, 0, stream>>>(feats, trans, out);
}

// Round 8
// 3910.177 us; speedup vs baseline: 1.2203x; 1.2203x over previous
//
#include <hip/hip_runtime.h>
#include <hip/hip_bf16.h>

// Problem constants
#define BB 32
#define SS 512
#define DD 256
#define HH 256
#define GG 1024          // 4*H
#define MM (SS*BB)       // 16384 rows, m = s*32 + b
#define NSENT 16
#define TT 12
#define TAG_START 10
#define TAG_STOP 11

typedef unsigned long long u64;
typedef unsigned int u32;

__device__ __forceinline__ float sigm(float x) {
  x = fminf(fmaxf(x, -15.f), 15.f);
  return 1.f / (1.f + __expf(-x));
}
__device__ __forceinline__ float tanh_fast(float x) {
  x = fminf(fmaxf(x, -15.f), 15.f);
  float e = __expf(2.f * x);
  return (e - 1.f) / (e + 1.f);
}

// ---------------- embed gather: X1[m][d] = embed[inputs[b][s]][d], m = s*32+b
__global__ void embed_kernel(const int* __restrict__ toks, const float* __restrict__ emb,
                             float* __restrict__ X1) {
  int m = blockIdx.x;
  int s = m >> 5, b = m & 31;
  int tok = toks[b * SS + s];
  ((float4*)(X1 + (size_t)m * DD))[threadIdx.x] =
      ((const float4*)(emb + (size_t)tok * DD))[threadIdx.x];
}

// ---------------- fp32 NT GEMM (R9-verified core + z-batching):
// C[M,N] = A[M,K](lda) @ W[N,K](ldw)^T + bias.  128x128 tile, 8x8/thread.
// blockIdx.z selects direction: W += z*wz, C += z*cz, bias += z*GG.
__launch_bounds__(256)
__global__ void gemm_nt(const float* __restrict__ A, const float* __restrict__ W_,
                        const float* __restrict__ bias_, float* __restrict__ C_,
                        int K, int lda, int ldw, int ldC, size_t wz, size_t cz) {
  __shared__ float As[16 * 132];
  __shared__ float Ws[16 * 132];
  const float* W = W_ + (size_t)blockIdx.z * wz;
  const float* bias = bias_ ? bias_ + (size_t)blockIdx.z * GG : nullptr;
  float* C = C_ + (size_t)blockIdx.z * cz;
  const int tid = threadIdx.x;
  const int n0 = blockIdx.x * 128, m0 = blockIdx.y * 128;
  const int row = tid & 127, half = tid >> 7;    // staging: 128 rows x 2 k-halves
  const int tx = tid & 15, ty = tid >> 4;        // compute: 16x16 thread grid
  float acc[8][8] = {};
  const float* Arow = A + (size_t)(m0 + row) * lda;
  const float* Wrow = W + (size_t)(n0 + row) * ldw;
  for (int kk = 0; kk < K; kk += 16) {
    const int kb = half * 8;
    float4 a0 = *(const float4*)(Arow + kk + kb);
    float4 a1 = *(const float4*)(Arow + kk + kb + 4);
    float4 w0 = *(const float4*)(Wrow + kk + kb);
    float4 w1 = *(const float4*)(Wrow + kk + kb + 4);
    As[(kb + 0) * 132 + row] = a0.x; As[(kb + 1) * 132 + row] = a0.y;
    As[(kb + 2) * 132 + row] = a0.z; As[(kb + 3) * 132 + row] = a0.w;
    As[(kb + 4) * 132 + row] = a1.x; As[(kb + 5) * 132 + row] = a1.y;
    As[(kb + 6) * 132 + row] = a1.z; As[(kb + 7) * 132 + row] = a1.w;
    Ws[(kb + 0) * 132 + row] = w0.x; Ws[(kb + 1) * 132 + row] = w0.y;
    Ws[(kb + 2) * 132 + row] = w0.z; Ws[(kb + 3) * 132 + row] = w0.w;
    Ws[(kb + 4) * 132 + row] = w1.x; Ws[(kb + 5) * 132 + row] = w1.y;
    Ws[(kb + 6) * 132 + row] = w1.z; Ws[(kb + 7) * 132 + row] = w1.w;
    __syncthreads();
#pragma unroll
    for (int kl = 0; kl < 16; ++kl) {
      const float4 alo = *(const float4*)&As[kl * 132 + ty * 4];
      const float4 ahi = *(const float4*)&As[kl * 132 + 64 + ty * 4];
      const float4 wlo = *(const float4*)&Ws[kl * 132 + tx * 4];
      const float4 whi = *(const float4*)&Ws[kl * 132 + 64 + tx * 4];
      const float am[8] = {alo.x, alo.y, alo.z, alo.w, ahi.x, ahi.y, ahi.z, ahi.w};
      const float wm[8] = {wlo.x, wlo.y, wlo.z, wlo.w, whi.x, whi.y, whi.z, whi.w};
#pragma unroll
      for (int i = 0; i < 8; ++i)
#pragma unroll
        for (int j = 0; j < 8; ++j) acc[i][j] = fmaf(am[i], wm[j], acc[i][j]);
    }
    __syncthreads();
  }
  float4 blo = make_float4(0.f, 0.f, 0.f, 0.f), bhi = blo;
  if (bias) {
    blo = *(const float4*)(bias + n0 + tx * 4);
    bhi = *(const float4*)(bias + n0 + 64 + tx * 4);
  }
#pragma unroll
  for (int i = 0; i < 8; ++i) {
    const int m = m0 + ((i < 4) ? (ty * 4 + i) : (64 + ty * 4 + i - 4));
    float4 lo = make_float4(acc[i][0] + blo.x, acc[i][1] + blo.y,
                            acc[i][2] + blo.z, acc[i][3] + blo.w);
    float4 hi = make_float4(acc[i][4] + bhi.x, acc[i][5] + bhi.y,
                            acc[i][6] + bhi.z, acc[i][7] + bhi.w);
    *(float4*)(C + (size_t)m * ldC + n0 + tx * 4) = lo;
    *(float4*)(C + (size_t)m * ldC + n0 + 64 + tx * 4) = hi;
  }
}

// ---------------- whh repack (R3-verified layout): [d][sl][i4(32)][t(256)][4],
// t = half*128 + r; value = whh[d][gcol(r,sl)][half*128 + i4*4 + c].
__global__ void prep_whh(const float* __restrict__ whh1, const float* __restrict__ whh2,
                         float* __restrict__ o1, float* __restrict__ o2) {
  int idx0 = blockIdx.x * 256 + threadIdx.x;       // 2 * 524288
  int layer = idx0 >> 19;
  int idx = idx0 & 524287;
  const float* whh = layer ? whh2 : whh1;
  float* out = layer ? o2 : o1;
  int c    = idx & 3;
  int t    = (idx >> 2) & 255;
  int i4   = (idx >> 10) & 31;
  int sl   = (idx >> 15) & 7;
  int d    = idx >> 18;
  int r    = t & 127;
  int half = t >> 7;
  int g = (r >> 5) * 256 + sl * 32 + (r & 31);
  int k = half * 128 + i4 * 4 + c;
  out[idx] = whh[(size_t)(d * GG + g) * HH + k];
}

// ---------------- attadd: Xp[d][m][g] += sum_n aw[m][n] * sentW[d][(m&31)*16+n][g]
// (R4-verified kernel: rank-16 attention folded into Xp so rec2 == rec1 and the
// per-step spin path carries ZERO extra loads)
__global__ void attadd_kernel(const float* __restrict__ aw, const float* __restrict__ sentW,
                              float* __restrict__ Xp) {
  __shared__ float a[NSENT];
  const int idx = blockIdx.x;          // d*MM + m
  const int d = idx >> 14;             // MM = 16384 = 2^14
  const int m = idx & (MM - 1);
  const int b = m & 31;
  const int tid = threadIdx.x;
  if (tid < NSENT) a[tid] = aw[(size_t)m * 16 + tid];
  __syncthreads();
  const int g = tid * 4;
  float* xp = Xp + ((size_t)d * MM + m) * GG + g;
  const float* swp = sentW + ((size_t)d * 512 + b * 16) * 1024 + g;
  float4 acc = *(const float4*)xp;
#pragma unroll
  for (int n = 0; n < NSENT; ++n) {
    const float4 sw = *(const float4*)&swp[(size_t)n * 1024];
    acc.x = fmaf(a[n], sw.x, acc.x);
    acc.y = fmaf(a[n], sw.y, acc.y);
    acc.z = fmaf(a[n], sw.z, acc.z);
    acc.w = fmaf(a[n], sw.w, acc.w);
  }
  *(float4*)xp = acc;
}

// ---------------- LSTM recurrence — R6-verified comm protocol (256 thr,
// per-thread 2-word agent polls w/ s_sleep, k-split w[128] in VGPRs, p_lds
// combine, tid<64 epilogue single agent store, post-(c) hist, __syncthreads).
// R8 changes (both target the vmcnt FIFO ahead of the spin):
//  (1) NO attention in rec (attadd_kernel pre-folds it) -> no aw loads queued
//      before the spin; ~16 VGPR freed.
//  (2) xp prefetched ONE STEP AHEAD, issued after barrier (c): its HBM latency
//      (~900cy) hides under the NEXT spin instead of delaying first-detect.
__launch_bounds__(256, 1)
__global__ void rec_kernel(const float* __restrict__ Xp, const float* __restrict__ whh_p,
                           float* __restrict__ hist, u64* __restrict__ hx) {
  __shared__ float h_lds[512];       // [c*256 + k]
  __shared__ float p_lds[512];       // [(half*128 + r)*2 + c]
  const int tid = threadIdx.x;
  const int bid = blockIdx.x;
  const int sl = bid >> 5;
  const int db = bid & 31;
  const int d = db & 1;
  const int bg = db >> 1;
  const int r = tid & 127;           // gate row 0..127 (gate*32+j)
  const int half = tid >> 7;         // k-half: k in [half*128, half*128+128)
  // -------- register-resident whh half-row (w[128]/thread; ~160 VGPR, no spill)
  const float* wp = whh_p + (size_t)(d * 8 + sl) * 32768;
  float w[128];
#pragma unroll
  for (int i4 = 0; i4 < 32; ++i4) {
    const float4 v = *(const float4*)&wp[(size_t)(i4 * 256 + tid) * 4];
    w[i4 * 4 + 0] = v.x; w[i4 * 4 + 1] = v.y;
    w[i4 * 4 + 2] = v.z; w[i4 * 4 + 3] = v.w;
  }
  const float* XpD = Xp + (size_t)d * MM * GG;
  const int gcol = (r >> 5) * 256 + sl * 32 + (r & 31);
  const int jj = tid & 31, cc = tid >> 5;        // producer epilogue mapping (tid<64)
  const int histMine = ((r >> 4) == sl);         // my 2 polled words in my hist slice
  float creg = 0.f;                              // LSTM cell state (valid tid<64)
  // group base: hx[slot][d][bg][512]
  u64* grp[2] = { hx + ((size_t)(0 * 2 + d) * 16 + bg) * 512,
                  hx + ((size_t)(1 * 2 + d) * 16 + bg) * 512 };
  // prologue: xp prefetch for step 0 (half 0 owns the xp add)
  float xn0 = 0.f, xn1 = 0.f;
  if (half == 0) {
    const int s0 = d ? (SS - 1) : 0;
    const int m00 = s0 * BB + bg * 2;
    xn0 = XpD[(size_t)m00 * GG + gcol];
    xn1 = XpD[(size_t)(m00 + 1) * GG + gcol];
  }
#pragma unroll 1
  for (int t = 0; t < SS; ++t) {
    const float x0 = xn0, x1 = xn1;  // xp for THIS step (prefetched last iter)
    // ---- per-thread barrier-free spin on my 2 tagged words (R6-exact) ----
    u64 w0, w1;
    {
      u64* base = grp[t & 1] + tid * 2;
      w0 = __hip_atomic_load(base + 0, __ATOMIC_RELAXED, __HIP_MEMORY_SCOPE_AGENT);
      w1 = __hip_atomic_load(base + 1, __ATOMIC_RELAXED, __HIP_MEMORY_SCOPE_AGENT);
      while (((u32)(w0 >> 32) != (u32)t) | ((u32)(w1 >> 32) != (u32)t)) {
        __builtin_amdgcn_s_sleep(1);
        w0 = __hip_atomic_load(base + 0, __ATOMIC_RELAXED, __HIP_MEMORY_SCOPE_AGENT);
        w1 = __hip_atomic_load(base + 1, __ATOMIC_RELAXED, __HIP_MEMORY_SCOPE_AGENT);
      }
    }
    *(float2*)&h_lds[tid * 2] = make_float2(__uint_as_float((u32)w0),
                                            __uint_as_float((u32)w1));
    __syncthreads();   // (b) h_lds complete
    {
      // matvec: 4 independent accumulator chains; w from regs, h broadcast LDS
      const int kb = half * 128;
      float p0a = 0.f, p0b = 0.f, p1a = 0.f, p1b = 0.f;
#pragma unroll
      for (int k8 = 0; k8 < 16; ++k8) {
        const float4 h0a = *(const float4*)&h_lds[kb + k8 * 8];
        const float4 h0b = *(const float4*)&h_lds[kb + k8 * 8 + 4];
        const float4 h1a = *(const float4*)&h_lds[256 + kb + k8 * 8];
        const float4 h1b = *(const float4*)&h_lds[256 + kb + k8 * 8 + 4];
        p0a = fmaf(w[k8*8+0], h0a.x, p0a); p0a = fmaf(w[k8*8+1], h0a.y, p0a);
        p0a = fmaf(w[k8*8+2], h0a.z, p0a); p0a = fmaf(w[k8*8+3], h0a.w, p0a);
        p0b = fmaf(w[k8*8+4], h0b.x, p0b); p0b = fmaf(w[k8*8+5], h0b.y, p0b);
        p0b = fmaf(w[k8*8+6], h0b.z, p0b); p0b = fmaf(w[k8*8+7], h0b.w, p0b);
        p1a = fmaf(w[k8*8+0], h1a.x, p1a); p1a = fmaf(w[k8*8+1], h1a.y, p1a);
        p1a = fmaf(w[k8*8+2], h1a.z, p1a); p1a = fmaf(w[k8*8+3], h1a.w, p1a);
        p1b = fmaf(w[k8*8+4], h1b.x, p1b); p1b = fmaf(w[k8*8+5], h1b.y, p1b);
        p1b = fmaf(w[k8*8+6], h1b.z, p1b); p1b = fmaf(w[k8*8+7], h1b.w, p1b);
      }
      *(float2*)&p_lds[tid * 2] = make_float2(p0a + p0b + x0, p1a + p1b + x1);
    }
    __syncthreads();   // (c) p_lds ready; fences h_lds reads vs next-step writes
    if (tid < 64) {    // producer epilogue: combine k-halves, one 8B L3 atomic
      const float iv = p_lds[(jj) * 2 + cc]       + p_lds[(128 + jj) * 2 + cc];
      const float fv = p_lds[(32 + jj) * 2 + cc]  + p_lds[(128 + 32 + jj) * 2 + cc];
      const float gv = p_lds[(64 + jj) * 2 + cc]  + p_lds[(128 + 64 + jj) * 2 + cc];
      const float ov = p_lds[(96 + jj) * 2 + cc]  + p_lds[(128 + 96 + jj) * 2 + cc];
      const float cs = sigm(fv) * creg + sigm(iv) * tanh_fast(gv);
      creg = cs;
      const float hn = sigm(ov) * tanh_fast(cs);
      u64 wv = ((u64)(u32)(t + 1) << 32) | (u64)__float_as_uint(hn);
      __hip_atomic_store(grp[(t + 1) & 1] + cc * 256 + sl * 32 + jj, wv,
                         __ATOMIC_RELAXED, __HIP_MEMORY_SCOPE_AGENT);
    }
    // distributed hist write for step t-1 (post-(c), R6-verified spot)
    if (histMine && t > 0) {
      const int sp = d ? (SS - t) : (t - 1);
      *(float2*)&hist[(size_t)(sp * BB + bg * 2 + half) * 512 + d * 256 + r * 2] =
          make_float2(__uint_as_float((u32)w0), __uint_as_float((u32)w1));
    }
    // xp prefetch for t+1: issued post-(c) so its HBM latency hides under the
    // NEXT spin (not queued ahead of this step's — or any — tag-check loads)
    if (half == 0) {
      const int tn = (t + 1 < SS) ? (t + 1) : (SS - 1);
      const int sn = d ? (SS - 1 - tn) : tn;
      const int m0n = sn * BB + bg * 2;
      xn0 = XpD[(size_t)m0n * GG + gcol];
      xn1 = XpD[(size_t)(m0n + 1) * GG + gcol];
    }
  }
  // distributed final flush (tag SS): each participating thread polls its OWN words
  if (histMine) {
    u64* base = grp[SS & 1] + tid * 2;
    u64 w0, w1;
    do {
      w0 = __hip_atomic_load(base + 0, __ATOMIC_RELAXED, __HIP_MEMORY_SCOPE_AGENT);
      w1 = __hip_atomic_load(base + 1, __ATOMIC_RELAXED, __HIP_MEMORY_SCOPE_AGENT);
      if (((u32)(w0 >> 32) == (u32)SS) & ((u32)(w1 >> 32) == (u32)SS)) break;
      __builtin_amdgcn_s_sleep(1);
    } while (true);
    const int sp = d ? 0 : (SS - 1);
    *(float2*)&hist[(size_t)(sp * BB + bg * 2 + half) * 512 + d * 256 + r * 2] =
        make_float2(__uint_as_float((u32)w0), __uint_as_float((u32)w1));
  }
}

// ---------------- aw: scores over NS=16 sentence embs + softmax -> aw[m][16]
__global__ void aw_kernel(const float* __restrict__ wx, const float* __restrict__ sent,
                          float* __restrict__ awout) {
  __shared__ float sl[NSENT * 512];   // 32 KB
  __shared__ float wxr[512];
  __shared__ float parts[256];
  __shared__ float avals[NSENT];
  __shared__ float red0;
  const int tid = threadIdx.x;
  const int b = blockIdx.y;
  const int s0 = blockIdx.x * 32;
  for (int i = tid; i < NSENT * 512; i += 256) sl[i] = sent[(size_t)b * NSENT * 512 + i];
  __syncthreads();
  for (int si = 0; si < 32; ++si) {
    const int m = (s0 + si) * BB + b;
    for (int i = tid; i < 512; i += 256) wxr[i] = wx[(size_t)m * 512 + i];
    __syncthreads();
    const int n = tid >> 4, kp = tid & 15;
    float p = 0.f;
#pragma unroll 8
    for (int f = kp * 32; f < kp * 32 + 32; ++f) p = fmaf(wxr[f], sl[n * 512 + f], p);
    parts[tid] = p;
    __syncthreads();
    if (tid < NSENT) {
      float sc = 0.f;
      for (int qq = 0; qq < 16; ++qq) sc += parts[tid * 16 + qq];
      avals[tid] = sc;
    }
    __syncthreads();
    if (tid == 0) {
      float mx = avals[0];
      for (int qq = 1; qq < NSENT; ++qq) mx = fmaxf(mx, avals[qq]);
      float sm = 0.f;
      for (int qq = 0; qq < NSENT; ++qq) { float e = expf(avals[qq] - mx); avals[qq] = e; sm += e; }
      red0 = 1.f / sm;
    }
    __syncthreads();
    if (tid < NSENT) awout[(size_t)m * 16 + tid] = avals[tid] * red0;
    __syncthreads();
  }
}

// ---------------- feats[m][t] = l2m[m][:] . h2t_w[t][:] + h2t_b[t]; wave per row
__global__ void feats_kernel(const float* __restrict__ l2m, const float* __restrict__ w,
                             const float* __restrict__ bias, float* __restrict__ feats) {
  const int wave = threadIdx.x >> 6, lane = threadIdx.x & 63;
  const int m = blockIdx.x * 4 + wave;
  const float* row = l2m + (size_t)m * 512;
  float rv[8];
#pragma unroll
  for (int i = 0; i < 8; ++i) rv[i] = row[lane + i * 64];
  for (int t = 0; t < TT; ++t) {
    const float* wr = w + t * 512;
    float p = 0.f;
#pragma unroll
    for (int i = 0; i < 8; ++i) p = fmaf(rv[i], wr[lane + i * 64], p);
#pragma unroll
    for (int off = 32; off; off >>= 1) p += __shfl_down(p, off);
    if (lane == 0) feats[(size_t)m * TT + t] = p + bias[t];
  }
}

// ---------------- viterbi per batch; 1 wave, whole DP in LDS
__global__ void viterbi_kernel(const float* __restrict__ feats, const float* __restrict__ trans,
                               int* __restrict__ out) {
  __shared__ float flds[SS * TT];
  __shared__ unsigned char bp[SS * TT];
  __shared__ float tr[TT * TT];
  __shared__ float fv[TT];
  __shared__ float tv[TT];
  __shared__ int pathS[SS];
  const int b = blockIdx.x, tid = threadIdx.x;
  for (int i = tid; i < SS * TT; i += 64) {
    int s = i / TT, t = i - s * TT;
    flds[i] = feats[(size_t)(s * BB + b) * TT + t];
  }
  for (int i = tid; i < TT * TT; i += 64) tr[i] = trans[i];
  if (tid < TT) fv[tid] = (tid == TAG_START) ? 0.f : -10000.f;
  __syncthreads();
  for (int s = 0; s < SS; ++s) {
    float nf = 0.f;
    if (tid < TT) {
      float mx = -1e30f;
      int bj = 0;
#pragma unroll
      for (int jj = 0; jj < TT; ++jj) {
        float v = fv[jj] + tr[tid * TT + jj];
        if (v > mx) { mx = v; bj = jj; }
      }
      nf = mx + flds[s * TT + tid];
      bp[s * TT + tid] = (unsigned char)bj;
    }
    __syncthreads();
    if (tid < TT) fv[tid] = nf;
    __syncthreads();
  }
  if (tid < TT) tv[tid] = fv[tid] + tr[TAG_STOP * TT + tid];
  __syncthreads();
  if (tid == 0) {
    int best = 0;
    float mx = tv[0];
    for (int jj = 1; jj < TT; ++jj)
      if (tv[jj] > mx) { mx = tv[jj]; best = jj; }
    pathS[SS - 1] = best;
    for (int s = SS - 1; s > 0; --s) { best = bp[s * TT + best]; pathS[s - 1] = best; }
  }
  __syncthreads();
  for (int s = tid; s < SS; s += 64) out[b * SS + s] = pathS[s];
}

// ---------------- workspace layout (bytes) — total ~245.6 MB < 256 MB ----------------
#define OFF_XP    ((size_t)0)               // 2*16384*1024*4 = 134217728
#define OFF_WX    ((size_t)134217728)       // 16384*512*4 = 33554432
#define OFF_L2M   ((size_t)167772160)       // 16384*512*4 = 33554432 (X1 aliases here)
#define OFF_WORD  ((size_t)201326592)       // 16384*512*4 = 33554432
#define OFF_WT1   ((size_t)234881024)       // 2097152
#define OFF_WT2   ((size_t)236978176)       // 2097152
#define OFF_FEATS ((size_t)239075328)       // 786432
#define OFF_HX1   ((size_t)239861760)       // 262144
#define OFF_HX2   ((size_t)240123904)       // 262144
#define OFF_SENTW ((size_t)240386048)       // 2*512*1024*4 = 4194304
#define OFF_AW    ((size_t)244580352)       // 16384*16*4 = 1048576

extern "C" void kernel_launch(void* const* d_in, const int* in_sizes, int n_in,
                              void* d_out, int out_size, void* d_ws, size_t ws_size,
                              hipStream_t stream) {
  const int* inputs  = (const int*)d_in[0];
  const float* sent  = (const float*)d_in[1];
  const float* emb   = (const float*)d_in[2];
  const float* l1wih = (const float*)d_in[3];
  const float* l1whh = (const float*)d_in[4];
  const float* l1b   = (const float*)d_in[5];
  const float* l2wih = (const float*)d_in[6];
  const float* l2whh = (const float*)d_in[7];
  const float* l2b   = (const float*)d_in[8];
  const float* attW  = (const float*)d_in[9];
  const float* h2tw  = (const float*)d_in[10];
  const float* h2tb  = (const float*)d_in[11];
  const float* trans = (const float*)d_in[12];
  int* out = (int*)d_out;
  char* ws = (char*)d_ws;

  float* Xp    = (float*)(ws + OFF_XP);
  float* wx    = (float*)(ws + OFF_WX);
  float* l2m   = (float*)(ws + OFF_L2M);
  float* X1    = l2m;    // X1 dead (read only by l1 gemms) before rec2 writes l2m
  float* word  = (float*)(ws + OFF_WORD);
  float* wt1   = (float*)(ws + OFF_WT1);
  float* wt2   = (float*)(ws + OFF_WT2);
  float* feats = (float*)(ws + OFF_FEATS);
  u64* hx1     = (u64*)(ws + OFF_HX1);
  u64* hx2     = (u64*)(ws + OFF_HX2);
  float* sentW = (float*)(ws + OFF_SENTW);
  float* awb   = (float*)(ws + OFF_AW);

  // zero both tagged-h buffers (contiguous 512 KB): tag 0 == "h_{-1}=0 ready"
  (void)hipMemsetAsync(ws + OFF_HX1, 0, 262144 * 2, stream);

  prep_whh<<<4096, 256, 0, stream>>>(l1whh, l2whh, wt1, wt2);
  // sentW[d][b*16+n][g] = sent[b][n][:512] . l2wih[d][g][512:1024]
  gemm_nt<<<dim3(8, 4, 2), 256, 0, stream>>>(sent, l2wih + 512, nullptr, sentW,
                                             512, 512, GG, 1024,
                                             (size_t)GG * GG, (size_t)512 * 1024);
  embed_kernel<<<MM, 64, 0, stream>>>(inputs, emb, X1);
  gemm_nt<<<dim3(8, 128, 2), 256, 0, stream>>>(X1, l1wih, l1b, Xp,
                                               DD, DD, DD, GG,
                                               (size_t)GG * DD, (size_t)MM * GG);
  rec_kernel<<<256, 256, 0, stream>>>(Xp, wt1, word, hx1);
  // wx = word @ attW^T
  gemm_nt<<<dim3(4, 128, 1), 256, 0, stream>>>(word, attW, nullptr, wx,
                                               512, 512, 512, 512, 0, 0);
  aw_kernel<<<dim3(16, 32), 256, 0, stream>>>(wx, sent, awb);
  // Xp2 = wx @ l2wih[:, :512]^T + bias
  gemm_nt<<<dim3(8, 128, 2), 256, 0, stream>>>(wx, l2wih, l2b, Xp,
                                               512, 512, GG, GG,
                                               (size_t)GG * GG, (size_t)MM * GG);
  // fold rank-16 attention into Xp (off rec2's per-step critical path)
  attadd_kernel<<<2 * MM, 256, 0, stream>>>(awb, sentW, Xp);
  rec_kernel<<<256, 256, 0, stream>>>(Xp, wt2, l2m, hx2);
  feats_kernel<<<MM / 4, 256, 0, stream>>>(l2m, h2tw, h2tb, feats);
  viterbi_kernel<<<BB, 64, 0, stream>>>(feats, trans, out);
}